// Round 4
// baseline (21972.763 us; speedup 1.0000x reference)
//
#include <hip/hip_runtime.h>
#include <cstdint>
#include <cstddef>

// Problem constants (fixed by the reference)
#define DD 1024
#define TT 2048
#define NL 4
// Recurrence: 256 blocks x 512 threads, 1 block/CU (LDS-padded to enforce).
#define NBLK 256
#define NTHR 512
// x-part GEMM tiles
#define GT 128
#define GC 128
#define GK 16

__device__ __forceinline__ float fast_tanh(float x) {
  float e = __expf(2.f * x);
  return 1.f - 2.f / (e + 1.f);
}

__global__ __launch_bounds__(1024) void prep_kernel(
    const float* __restrict__ sp, const float* __restrict__ rn_p,
    const float* __restrict__ w, const float* __restrict__ b,
    float* __restrict__ X0) {
  int i = blockIdx.x * blockDim.x + threadIdx.x;   // over T*D
  float rn = rn_p[0];
  int c = i & (DD - 1);
  X0[i] = sp[i] + rn * w[c] + b[c];
}

// ZX[t][piece*1024 + c] = sum_k X[t][k] * W[piece][k][c] + b[piece][c]
// using only the x-rows (0..1023) of each [2D, D] weight matrix.
__global__ __launch_bounds__(256) void xgemm_kernel(
    const float* __restrict__ X,    // [TT, DD]
    const float* __restrict__ Wf1, const float* __restrict__ Wf2,
    const float* __restrict__ Wta, const float* __restrict__ Wtb,
    const float* __restrict__ bf1, const float* __restrict__ bf2,
    const float* __restrict__ bta, const float* __restrict__ btb,
    float* __restrict__ ZX, int layer)
{
  __shared__ float As[GK][GT + 4];   // [k][t-row], padded
  __shared__ float Bs[GK][GC + 4];   // [k][col],  padded

  const int tid = threadIdx.x;
  const int ct = blockIdx.x;                 // col tile 0..31
  const int rt = blockIdx.y;                 // row tile 0..15
  const int c0 = ct * GC;                    // virtual col 0..4095
  const int B  = c0 >> 10;                   // weight piece
  const int cc0 = c0 & (DD - 1);
  const float* Wsel = (B == 0) ? Wf1 : (B == 1) ? Wf2 : (B == 2) ? Wta : Wtb;
  const float* bsel = (B == 0) ? bf1 : (B == 1) ? bf2 : (B == 2) ? bta : btb;
  const float* Wb = Wsel + (size_t)layer * 2 * DD * DD;   // x rows 0..1023
  const float* bb = bsel + (size_t)layer * DD + cc0;

  const int ty = tid >> 4, tx = tid & 15;    // 16x16 thread grid, 8x8 micro

  float acc[8][8];
#pragma unroll
  for (int i = 0; i < 8; ++i)
#pragma unroll
    for (int j = 0; j < 8; ++j) acc[i][j] = 0.f;

  for (int k0 = 0; k0 < DD; k0 += GK) {
    // Stage X chunk transposed: As[k][r]
#pragma unroll
    for (int j = 0; j < 2; ++j) {
      int idx = j * 256 + tid;               // 0..511
      int r = idx >> 2;                      // 0..127
      int kq = (idx & 3) * 4;                // 0,4,8,12
      float4 v = *(const float4*)&X[(size_t)(rt * GT + r) * DD + k0 + kq];
      As[kq + 0][r] = v.x; As[kq + 1][r] = v.y;
      As[kq + 2][r] = v.z; As[kq + 3][r] = v.w;
    }
    // Stage W chunk: Bs[k][c]
#pragma unroll
    for (int j = 0; j < 2; ++j) {
      int idx = j * 256 + tid;
      int kk = idx >> 5;                     // 0..15
      int cq = (idx & 31) * 4;               // 0..124
      *(float4*)&Bs[kk][cq] =
          *(const float4*)&Wb[(size_t)(k0 + kk) * DD + cc0 + cq];
    }
    __syncthreads();
#pragma unroll
    for (int k = 0; k < GK; ++k) {
      float a[8], bv[8];
      *(float4*)&a[0]  = *(const float4*)&As[k][ty * 8];
      *(float4*)&a[4]  = *(const float4*)&As[k][ty * 8 + 4];
      *(float4*)&bv[0] = *(const float4*)&Bs[k][tx * 8];
      *(float4*)&bv[4] = *(const float4*)&Bs[k][tx * 8 + 4];
#pragma unroll
      for (int i = 0; i < 8; ++i)
#pragma unroll
        for (int j = 0; j < 8; ++j) acc[i][j] = fmaf(a[i], bv[j], acc[i][j]);
    }
    __syncthreads();
  }

  float bias[8];
#pragma unroll
  for (int j = 0; j < 8; ++j) bias[j] = bb[tx * 8 + j];
#pragma unroll
  for (int i = 0; i < 8; ++i) {
    int t = rt * GT + ty * 8 + i;
    float4 o0 = make_float4(acc[i][0] + bias[0], acc[i][1] + bias[1],
                            acc[i][2] + bias[2], acc[i][3] + bias[3]);
    float4 o1 = make_float4(acc[i][4] + bias[4], acc[i][5] + bias[5],
                            acc[i][6] + bias[6], acc[i][7] + bias[7]);
    *(float4*)&ZX[(size_t)t * 4096 + c0 + tx * 8]     = o0;
    *(float4*)&ZX[(size_t)t * 4096 + c0 + tx * 8 + 4] = o1;
  }
}

// h-part recurrence. Block bid owns out-cols [bid*4, bid*4+4) = 16 z-cols.
// W_h (rows 1024..2047 of each matrix) lives in LDS (64 KB). Per step each
// wave prefetches its 8 float4 weight rows from LDS + the ZX value BEFORE
// polling h_{t-1}; consumers poll the h DATA (NaN-prefilled buffer; h is
// always finite) with agent-scope atomics.
__global__ __launch_bounds__(NTHR) void recur_kernel(
    const float* __restrict__ ZX,   // [TT, 4096], x-part incl. bias
    float* __restrict__ Hout,       // [TT, DD], NaN-prefilled
    const float* __restrict__ Wf1, const float* __restrict__ Wf2,
    const float* __restrict__ Wta, const float* __restrict__ Wtb,
    const float* __restrict__ dt_p, int layer,
    float* __restrict__ out_last)
{
  __shared__ float4 wlds[8 * 8 * 64];  // [wave][seg][lane] = 64 KB
  __shared__ float hs[DD];             // h_{t-1} broadcast (4 KB)
  __shared__ float zbuf[16];
  __shared__ float pad[4096];          // +16 KB -> 84 KB total -> 1 block/CU

  const int tid = threadIdx.x;
  const int w   = tid >> 6;            // wave 0..7
  const int ln  = tid & 63;
  const int bid = blockIdx.x;

  const int B    = w >> 1;
  const int p    = w & 1;
  const int col0 = bid * 4 + 2 * p;    // this wave's 2 cols (of piece B)
  const float* Wsel = (B == 0) ? Wf1 : (B == 1) ? Wf2 : (B == 2) ? Wta : Wtb;
  const float* Wb = Wsel + (size_t)layer * 2 * DD * DD;
  const float dtv = dt_p[0];
  if (dtv == -1.2345e30f) pad[tid] = 0.f;  // keep pad alive (never true)

  // Fill W_h into LDS: rows 1024 + seg*128 + 2*ln (+1), cols col0, col0+1.
#pragma unroll
  for (int s = 0; s < 8; ++s) {
    const float* a_ = Wb + (size_t)(DD + s * 128 + 2 * ln) * DD + col0;
    float2 lo = *(const float2*)a_;
    float2 hi = *(const float2*)(a_ + DD);
    wlds[(w * 8 + s) * 64 + ln] = make_float4(lo.x, lo.y, hi.x, hi.y);
  }
  __syncthreads();

  for (int t = 0; t < TT; ++t) {
    // Issue latency-hiding loads first: ZX (global) + weights (LDS).
    float2 zx2 = make_float2(0.f, 0.f);
    if (ln == 0) zx2 = *(const float2*)&ZX[(size_t)t * 4096 + B * 1024 + col0];
    float4 m0 = wlds[(w * 8 + 0) * 64 + ln];
    float4 m1 = wlds[(w * 8 + 1) * 64 + ln];
    float4 m2 = wlds[(w * 8 + 2) * 64 + ln];
    float4 m3 = wlds[(w * 8 + 3) * 64 + ln];
    float4 m4 = wlds[(w * 8 + 4) * 64 + ln];
    float4 m5 = wlds[(w * 8 + 5) * 64 + ln];
    float4 m6 = wlds[(w * 8 + 6) * 64 + ln];
    float4 m7 = wlds[(w * 8 + 7) * 64 + ln];

    // Poll own h-pair of step t-1 (data IS the flag: NaN = not yet written).
    float h0 = 0.f, h1 = 0.f;
    if (t > 0) {
      const unsigned long long* hp =
          (const unsigned long long*)&Hout[(size_t)(t - 1) * DD + 2 * tid];
      unsigned long long v; int guard = 0;
      do {
        v = __hip_atomic_load(hp, __ATOMIC_RELAXED, __HIP_MEMORY_SCOPE_AGENT);
        unsigned lo = (unsigned)v, hi = (unsigned)(v >> 32);
        if (((lo & 0x7fffffffu) <= 0x7f800000u) &&
            ((hi & 0x7fffffffu) <= 0x7f800000u)) break;
      } while (++guard < (1 << 22));
      h0 = __uint_as_float((unsigned)v);
      h1 = __uint_as_float((unsigned)(v >> 32));
    }
    *(float2*)&hs[2 * tid] = make_float2(h0, h1);
    __syncthreads();   // hs ready (prev step's zbuf reads already done)

    float acc0 = 0.f, acc1 = 0.f;
#define DOTS(s, m) do {                                   \
      float2 v_ = *(const float2*)&hs[(s) * 128 + 2 * ln];\
      acc0 = fmaf(v_.x, m.x, acc0);                       \
      acc0 = fmaf(v_.y, m.z, acc0);                       \
      acc1 = fmaf(v_.x, m.y, acc1);                       \
      acc1 = fmaf(v_.y, m.w, acc1);                       \
    } while (0)
    DOTS(0, m0); DOTS(1, m1); DOTS(2, m2); DOTS(3, m3);
    DOTS(4, m4); DOTS(5, m5); DOTS(6, m6); DOTS(7, m7);
#undef DOTS
#pragma unroll
    for (int off = 32; off > 0; off >>= 1) {
      acc0 += __shfl_xor(acc0, off, 64);
      acc1 += __shfl_xor(acc1, off, 64);
    }
    if (ln == 0) {
      zbuf[2 * w]     = acc0 + zx2.x;   // zbuf[B*4 + 2p + q]
      zbuf[2 * w + 1] = acc1 + zx2.y;
    }
    __syncthreads();   // zbuf ready; hs(t) reads done -> next write safe

    if (tid < 4) {
      float z1 = zbuf[tid];
      float z2 = zbuf[4 + tid];
      float za = zbuf[8 + tid];
      float zb = zbuf[12 + tid];
      float f1 = fast_tanh(z1);
      float f2 = fast_tanh(z2);
      float g = 1.f / (1.f + __expf(za * dtv - zb));  // sigmoid(-za*dt+zb)
      float h = g * f1 + (1.f - g) * f2;
      int col = bid * 4 + tid;
      __hip_atomic_store(&Hout[(size_t)t * DD + col], h,
                         __ATOMIC_RELAXED, __HIP_MEMORY_SCOPE_AGENT);
      if (out_last && t == TT - 1) out_last[col] = h;
    }
  }
}

extern "C" void kernel_launch(void* const* d_in, const int* in_sizes, int n_in,
                              void* d_out, int out_size, void* d_ws, size_t ws_size,
                              hipStream_t stream) {
  const float* sp  = (const float*)d_in[0];
  const float* rn  = (const float*)d_in[1];
  const float* dt  = (const float*)d_in[2];
  const float* rw  = (const float*)d_in[3];
  const float* rb  = (const float*)d_in[4];
  const float* Wf1 = (const float*)d_in[5];
  const float* bf1 = (const float*)d_in[6];
  const float* Wf2 = (const float*)d_in[7];
  const float* bf2 = (const float*)d_in[8];
  const float* Wta = (const float*)d_in[9];
  const float* bta = (const float*)d_in[10];
  const float* Wtb = (const float*)d_in[11];
  const float* btb = (const float*)d_in[12];

  float* ws = (float*)d_ws;
  float* A   = ws;                          // [TT, DD]
  float* Bb  = ws + (size_t)TT * DD;        // [TT, DD]
  float* ZX  = ws + (size_t)2 * TT * DD;    // [TT, 4096]
  float* out = (float*)d_out;
  const size_t seqBytes = sizeof(float) * TT * DD;

  dim3 ggrid(32, 16);

  // L0: input X0 -> A; h-seq -> Bb
  hipMemsetAsync(Bb, 0xFF, seqBytes, stream);
  prep_kernel<<<(TT * DD) / 1024, 1024, 0, stream>>>(sp, rn, rw, rb, A);
  xgemm_kernel<<<ggrid, 256, 0, stream>>>(A, Wf1, Wf2, Wta, Wtb,
      bf1, bf2, bta, btb, ZX, 0);
  recur_kernel<<<NBLK, NTHR, 0, stream>>>(ZX, Bb, Wf1, Wf2, Wta, Wtb,
      dt, 0, nullptr);
  // L1: Bb -> A
  hipMemsetAsync(A, 0xFF, seqBytes, stream);
  xgemm_kernel<<<ggrid, 256, 0, stream>>>(Bb, Wf1, Wf2, Wta, Wtb,
      bf1, bf2, bta, btb, ZX, 1);
  recur_kernel<<<NBLK, NTHR, 0, stream>>>(ZX, A, Wf1, Wf2, Wta, Wtb,
      dt, 1, nullptr);
  // L2: A -> Bb
  hipMemsetAsync(Bb, 0xFF, seqBytes, stream);
  xgemm_kernel<<<ggrid, 256, 0, stream>>>(A, Wf1, Wf2, Wta, Wtb,
      bf1, bf2, bta, btb, ZX, 2);
  recur_kernel<<<NBLK, NTHR, 0, stream>>>(ZX, Bb, Wf1, Wf2, Wta, Wtb,
      dt, 2, nullptr);
  // L3: Bb -> A, final h -> out
  hipMemsetAsync(A, 0xFF, seqBytes, stream);
  xgemm_kernel<<<ggrid, 256, 0, stream>>>(Bb, Wf1, Wf2, Wta, Wtb,
      bf1, bf2, bta, btb, ZX, 3);
  recur_kernel<<<NBLK, NTHR, 0, stream>>>(ZX, A, Wf1, Wf2, Wta, Wtb,
      dt, 3, out);
}

// Round 5
// 20297.835 us; speedup vs baseline: 1.0825x; 1.0825x over previous
//
#include <hip/hip_runtime.h>
#include <cstdint>
#include <cstddef>

// Problem constants (fixed by the reference)
#define DD 1024
#define TT 2048
#define NL 4
// Recurrence: 256 blocks x 512 threads (8 waves), 1 block/CU.
#define NBLK 256
#define NTHR 512
// x-part GEMM tiles
#define GT 128
#define GC 128
#define GK 16

__device__ __forceinline__ float fast_tanh(float x) {
  float e = __expf(2.f * x);
  return 1.f - 2.f / (e + 1.f);
}

// 16B agent-scope load (bypasses per-XCD L2 like __hip_atomic_load AGENT,
// but 4x wider -> 4x fewer EA requests in the poll loop).
__device__ __forceinline__ float4 agent_load16(const float* p) {
  float4 r;
  asm volatile("global_load_dwordx4 %0, %1, off sc1\n\t"
               "s_waitcnt vmcnt(0)"
               : "=v"(r) : "v"(p) : "memory");
  return r;
}

__global__ __launch_bounds__(1024) void prep_kernel(
    const float* __restrict__ sp, const float* __restrict__ rn_p,
    const float* __restrict__ w, const float* __restrict__ b,
    float* __restrict__ X0) {
  int i = blockIdx.x * blockDim.x + threadIdx.x;   // over T*D
  float rn = rn_p[0];
  int c = i & (DD - 1);
  X0[i] = sp[i] + rn * w[c] + b[c];
}

// ZX[t][piece*1024 + c] = sum_k X[t][k] * W[piece][k][c] + b[piece][c]
// using only the x-rows (0..1023) of each [2D, D] weight matrix.
__global__ __launch_bounds__(256) void xgemm_kernel(
    const float* __restrict__ X,    // [TT, DD]
    const float* __restrict__ Wf1, const float* __restrict__ Wf2,
    const float* __restrict__ Wta, const float* __restrict__ Wtb,
    const float* __restrict__ bf1, const float* __restrict__ bf2,
    const float* __restrict__ bta, const float* __restrict__ btb,
    float* __restrict__ ZX, int layer)
{
  __shared__ float As[GK][GT + 4];   // [k][t-row], padded
  __shared__ float Bs[GK][GC + 4];   // [k][col],  padded

  const int tid = threadIdx.x;
  const int ct = blockIdx.x;                 // col tile 0..31
  const int rt = blockIdx.y;                 // row tile 0..15
  const int c0 = ct * GC;                    // virtual col 0..4095
  const int B  = c0 >> 10;                   // weight piece
  const int cc0 = c0 & (DD - 1);
  const float* Wsel = (B == 0) ? Wf1 : (B == 1) ? Wf2 : (B == 2) ? Wta : Wtb;
  const float* bsel = (B == 0) ? bf1 : (B == 1) ? bf2 : (B == 2) ? bta : btb;
  const float* Wb = Wsel + (size_t)layer * 2 * DD * DD;   // x rows 0..1023
  const float* bb = bsel + (size_t)layer * DD + cc0;

  const int ty = tid >> 4, tx = tid & 15;    // 16x16 thread grid, 8x8 micro

  float acc[8][8];
#pragma unroll
  for (int i = 0; i < 8; ++i)
#pragma unroll
    for (int j = 0; j < 8; ++j) acc[i][j] = 0.f;

  for (int k0 = 0; k0 < DD; k0 += GK) {
#pragma unroll
    for (int j = 0; j < 2; ++j) {
      int idx = j * 256 + tid;               // 0..511
      int r = idx >> 2;                      // 0..127
      int kq = (idx & 3) * 4;                // 0,4,8,12
      float4 v = *(const float4*)&X[(size_t)(rt * GT + r) * DD + k0 + kq];
      As[kq + 0][r] = v.x; As[kq + 1][r] = v.y;
      As[kq + 2][r] = v.z; As[kq + 3][r] = v.w;
    }
#pragma unroll
    for (int j = 0; j < 2; ++j) {
      int idx = j * 256 + tid;
      int kk = idx >> 5;                     // 0..15
      int cq = (idx & 31) * 4;               // 0..124
      *(float4*)&Bs[kk][cq] =
          *(const float4*)&Wb[(size_t)(k0 + kk) * DD + cc0 + cq];
    }
    __syncthreads();
#pragma unroll
    for (int k = 0; k < GK; ++k) {
      float a[8], bv[8];
      *(float4*)&a[0]  = *(const float4*)&As[k][ty * 8];
      *(float4*)&a[4]  = *(const float4*)&As[k][ty * 8 + 4];
      *(float4*)&bv[0] = *(const float4*)&Bs[k][tx * 8];
      *(float4*)&bv[4] = *(const float4*)&Bs[k][tx * 8 + 4];
#pragma unroll
      for (int i = 0; i < 8; ++i)
#pragma unroll
        for (int j = 0; j < 8; ++j) acc[i][j] = fmaf(a[i], bv[j], acc[i][j]);
    }
    __syncthreads();
  }

  float bias[8];
#pragma unroll
  for (int j = 0; j < 8; ++j) bias[j] = bb[tx * 8 + j];
#pragma unroll
  for (int i = 0; i < 8; ++i) {
    int t = rt * GT + ty * 8 + i;
    float4 o0 = make_float4(acc[i][0] + bias[0], acc[i][1] + bias[1],
                            acc[i][2] + bias[2], acc[i][3] + bias[3]);
    float4 o1 = make_float4(acc[i][4] + bias[4], acc[i][5] + bias[5],
                            acc[i][6] + bias[6], acc[i][7] + bias[7]);
    *(float4*)&ZX[(size_t)t * 4096 + c0 + tx * 8]     = o0;
    *(float4*)&ZX[(size_t)t * 4096 + c0 + tx * 8 + 4] = o1;
  }
}

// h-part recurrence. Block bid owns h cols [bid*4, bid*4+4) (16 z-cols).
// W_h in LDS (64 KB). Poll protocol: Hout NaN-prefilled; h always finite;
// waves 0..3 poll 1 KB each via 16B sc1 loads, distribute through LDS.
// Wave 7 does the gate math + h store (t-1) while waves 0..3 poll.
__global__ __launch_bounds__(NTHR) void recur_kernel(
    const float* __restrict__ ZX,   // [TT, 4096], x-part incl. bias
    float* __restrict__ Hout,       // [TT, DD], NaN-prefilled
    const float* __restrict__ Wf1, const float* __restrict__ Wf2,
    const float* __restrict__ Wta, const float* __restrict__ Wtb,
    const float* __restrict__ dt_p, int layer,
    float* __restrict__ out_last)
{
  __shared__ float4 wlds[8 * 8 * 64];  // [wave][seg][lane] = 64 KB
  __shared__ float hs[DD];             // h_{t-1} broadcast (4 KB)
  __shared__ float zbuf[16];

  const int tid = threadIdx.x;
  const int w   = tid >> 6;            // wave 0..7
  const int ln  = tid & 63;
  const int bid = blockIdx.x;

  const int B    = w >> 1;
  const int p    = w & 1;
  const int col0 = bid * 4 + 2 * p;    // this wave's 2 cols (of piece B)
  const float* Wsel = (B == 0) ? Wf1 : (B == 1) ? Wf2 : (B == 2) ? Wta : Wtb;
  const float* Wb = Wsel + (size_t)layer * 2 * DD * DD;
  const float dtv = dt_p[0];

  // Fill W_h into LDS: rows 1024 + s*128 + 2*ln (+1), cols col0, col0+1.
#pragma unroll
  for (int s = 0; s < 8; ++s) {
    const float* a_ = Wb + (size_t)(DD + s * 128 + 2 * ln) * DD + col0;
    float2 lo = *(const float2*)a_;
    float2 hi = *(const float2*)(a_ + DD);
    wlds[(w * 8 + s) * 64 + ln] = make_float4(lo.x, lo.y, hi.x, hi.y);
  }
  *(float2*)&hs[2 * tid] = make_float2(0.f, 0.f);   // h_{-1} = 0
  __syncthreads();

  for (int t = 0; t < TT; ++t) {
    // x-part z for this wave's 2 cols (consumed at the zbuf combine).
    float2 zx2 = make_float2(0.f, 0.f);
    if (ln == 0) zx2 = *(const float2*)&ZX[(size_t)t * 4096 + B * 1024 + col0];

    if (t > 0) {
      if (w == 7) {
        // Producer: gate math + store of h(t-1) (zbuf from prev iteration).
        if (ln < 4) {
          float z1 = zbuf[ln];
          float z2 = zbuf[4 + ln];
          float za = zbuf[8 + ln];
          float zb = zbuf[12 + ln];
          float f1 = fast_tanh(z1);
          float f2 = fast_tanh(z2);
          float g = 1.f / (1.f + __expf(za * dtv - zb));
          float h = g * f1 + (1.f - g) * f2;
          __hip_atomic_store(&Hout[(size_t)(t - 1) * DD + bid * 4 + ln], h,
                             __ATOMIC_RELAXED, __HIP_MEMORY_SCOPE_AGENT);
        }
      } else if (w < 4) {
        // Pollers: wave w covers h words [w*256, w*256+256), 16B per lane.
        const float* src = &Hout[(size_t)(t - 1) * DD + w * 256 + ln * 4];
        float4 v; int guard = 0;
        while (true) {
          v = agent_load16(src);
          unsigned a0 = __float_as_uint(v.x) & 0x7fffffffu;
          unsigned a1 = __float_as_uint(v.y) & 0x7fffffffu;
          unsigned a2 = __float_as_uint(v.z) & 0x7fffffffu;
          unsigned a3 = __float_as_uint(v.w) & 0x7fffffffu;
          bool ok = (a0 <= 0x7f800000u) && (a1 <= 0x7f800000u) &&
                    (a2 <= 0x7f800000u) && (a3 <= 0x7f800000u);
          if (__all(ok)) break;
          if (++guard > (1 << 22)) break;
          __builtin_amdgcn_s_sleep(1);
        }
        *(float4*)&hs[w * 256 + ln * 4] = v;
      }
    }
    __syncthreads();   // hs(t-1) ready

    // Dot: 2 cols per wave over the 1024 h rows (weights from LDS).
    float acc0 = 0.f, acc1 = 0.f;
#define DOTS(s) do {                                        \
      float4 m = wlds[(w * 8 + (s)) * 64 + ln];             \
      float2 v_ = *(const float2*)&hs[(s) * 128 + 2 * ln];  \
      acc0 = fmaf(v_.x, m.x, acc0);                         \
      acc0 = fmaf(v_.y, m.z, acc0);                         \
      acc1 = fmaf(v_.x, m.y, acc1);                         \
      acc1 = fmaf(v_.y, m.w, acc1);                         \
    } while (0)
    DOTS(0); DOTS(1); DOTS(2); DOTS(3);
    DOTS(4); DOTS(5); DOTS(6); DOTS(7);
#undef DOTS
#pragma unroll
    for (int off = 32; off > 0; off >>= 1) {
      acc0 += __shfl_xor(acc0, off, 64);
      acc1 += __shfl_xor(acc1, off, 64);
    }
    if (ln == 0) {
      zbuf[2 * w]     = acc0 + zx2.x;   // zbuf[B*4 + 2p + q]
      zbuf[2 * w + 1] = acc1 + zx2.y;
    }
    __syncthreads();   // zbuf(t) ready
  }

  // Epilogue: h(TT-1)
  if (w == 7 && ln < 4) {
    float z1 = zbuf[ln];
    float z2 = zbuf[4 + ln];
    float za = zbuf[8 + ln];
    float zb = zbuf[12 + ln];
    float f1 = fast_tanh(z1);
    float f2 = fast_tanh(z2);
    float g = 1.f / (1.f + __expf(za * dtv - zb));
    float h = g * f1 + (1.f - g) * f2;
    __hip_atomic_store(&Hout[(size_t)(TT - 1) * DD + bid * 4 + ln], h,
                       __ATOMIC_RELAXED, __HIP_MEMORY_SCOPE_AGENT);
    if (out_last) out_last[bid * 4 + ln] = h;
  }
}

extern "C" void kernel_launch(void* const* d_in, const int* in_sizes, int n_in,
                              void* d_out, int out_size, void* d_ws, size_t ws_size,
                              hipStream_t stream) {
  const float* sp  = (const float*)d_in[0];
  const float* rn  = (const float*)d_in[1];
  const float* dt  = (const float*)d_in[2];
  const float* rw  = (const float*)d_in[3];
  const float* rb  = (const float*)d_in[4];
  const float* Wf1 = (const float*)d_in[5];
  const float* bf1 = (const float*)d_in[6];
  const float* Wf2 = (const float*)d_in[7];
  const float* bf2 = (const float*)d_in[8];
  const float* Wta = (const float*)d_in[9];
  const float* bta = (const float*)d_in[10];
  const float* Wtb = (const float*)d_in[11];
  const float* btb = (const float*)d_in[12];

  float* ws = (float*)d_ws;
  float* A   = ws;                          // [TT, DD]
  float* Bb  = ws + (size_t)TT * DD;        // [TT, DD]
  float* ZX  = ws + (size_t)2 * TT * DD;    // [TT, 4096]
  float* out = (float*)d_out;
  const size_t seqBytes = sizeof(float) * TT * DD;

  dim3 ggrid(32, 16);

  // L0: X0 -> A; h-seq -> Bb
  hipMemsetAsync(Bb, 0xFF, seqBytes, stream);
  prep_kernel<<<(TT * DD) / 1024, 1024, 0, stream>>>(sp, rn, rw, rb, A);
  xgemm_kernel<<<ggrid, 256, 0, stream>>>(A, Wf1, Wf2, Wta, Wtb,
      bf1, bf2, bta, btb, ZX, 0);
  recur_kernel<<<NBLK, NTHR, 0, stream>>>(ZX, Bb, Wf1, Wf2, Wta, Wtb,
      dt, 0, nullptr);
  // L1: Bb -> A
  hipMemsetAsync(A, 0xFF, seqBytes, stream);
  xgemm_kernel<<<ggrid, 256, 0, stream>>>(Bb, Wf1, Wf2, Wta, Wtb,
      bf1, bf2, bta, btb, ZX, 1);
  recur_kernel<<<NBLK, NTHR, 0, stream>>>(ZX, A, Wf1, Wf2, Wta, Wtb,
      dt, 1, nullptr);
  // L2: A -> Bb
  hipMemsetAsync(Bb, 0xFF, seqBytes, stream);
  xgemm_kernel<<<ggrid, 256, 0, stream>>>(A, Wf1, Wf2, Wta, Wtb,
      bf1, bf2, bta, btb, ZX, 2);
  recur_kernel<<<NBLK, NTHR, 0, stream>>>(ZX, Bb, Wf1, Wf2, Wta, Wtb,
      dt, 2, nullptr);
  // L3: Bb -> A, final h -> out
  hipMemsetAsync(A, 0xFF, seqBytes, stream);
  xgemm_kernel<<<ggrid, 256, 0, stream>>>(Bb, Wf1, Wf2, Wta, Wtb,
      bf1, bf2, bta, btb, ZX, 3);
  recur_kernel<<<NBLK, NTHR, 0, stream>>>(ZX, A, Wf1, Wf2, Wta, Wtb,
      dt, 3, out);
}

// Round 7
// 19236.523 us; speedup vs baseline: 1.1422x; 1.0552x over previous
//
#include <hip/hip_runtime.h>
#include <cstdint>
#include <cstddef>

// Problem constants (fixed by the reference)
#define DD 1024
#define TT 2048
#define NL 4
// Recurrence: 256 blocks x 512 threads (8 waves), 1 block/CU.
#define NBLK 256
#define NTHR 512
// x-part GEMM tiles
#define GT 128
#define GC 128
#define GK 16

__device__ __forceinline__ float fast_tanh(float x) {
  float e = __expf(2.f * x);
  return 1.f - 2.f / (e + 1.f);
}

// 16B agent-scope load: bypasses the (non-coherent) per-XCD L2.
__device__ __forceinline__ float4 agent_load16(const float* p) {
  float4 r;
  asm volatile("global_load_dwordx4 %0, %1, off sc1\n\t"
               "s_waitcnt vmcnt(0)"
               : "=v"(r) : "v"(p) : "memory");
  return r;
}
// 16B agent-scope store as two 8B atomic stores (float4 asm input operands
// don't compile; 4B-granule atomicity is all the poll protocol needs).
__device__ __forceinline__ void agent_store16(float* p, float4 v) {
  unsigned long long lo =
      ((unsigned long long)__float_as_uint(v.y) << 32) | __float_as_uint(v.x);
  unsigned long long hi =
      ((unsigned long long)__float_as_uint(v.w) << 32) | __float_as_uint(v.z);
  __hip_atomic_store((unsigned long long*)p, lo,
                     __ATOMIC_RELAXED, __HIP_MEMORY_SCOPE_AGENT);
  __hip_atomic_store(((unsigned long long*)p) + 1, hi,
                     __ATOMIC_RELAXED, __HIP_MEMORY_SCOPE_AGENT);
}

__global__ __launch_bounds__(1024) void prep_kernel(
    const float* __restrict__ sp, const float* __restrict__ rn_p,
    const float* __restrict__ w, const float* __restrict__ b,
    float* __restrict__ X0) {
  int i = blockIdx.x * blockDim.x + threadIdx.x;   // over T*D
  float rn = rn_p[0];
  int c = i & (DD - 1);
  X0[i] = sp[i] + rn * w[c] + b[c];
}

// ZX[t][piece*1024 + c] = sum_k X[t][k] * W[piece][k][c] + b[piece][c]
__global__ __launch_bounds__(256) void xgemm_kernel(
    const float* __restrict__ X,    // [TT, DD]
    const float* __restrict__ Wf1, const float* __restrict__ Wf2,
    const float* __restrict__ Wta, const float* __restrict__ Wtb,
    const float* __restrict__ bf1, const float* __restrict__ bf2,
    const float* __restrict__ bta, const float* __restrict__ btb,
    float* __restrict__ ZX, int layer)
{
  __shared__ float As[GK][GT + 4];
  __shared__ float Bs[GK][GC + 4];

  const int tid = threadIdx.x;
  const int ct = blockIdx.x;                 // col tile 0..31
  const int rt = blockIdx.y;                 // row tile 0..15
  const int c0 = ct * GC;
  const int B  = c0 >> 10;
  const int cc0 = c0 & (DD - 1);
  const float* Wsel = (B == 0) ? Wf1 : (B == 1) ? Wf2 : (B == 2) ? Wta : Wtb;
  const float* bsel = (B == 0) ? bf1 : (B == 1) ? bf2 : (B == 2) ? bta : btb;
  const float* Wb = Wsel + (size_t)layer * 2 * DD * DD;   // x rows 0..1023
  const float* bb = bsel + (size_t)layer * DD + cc0;

  const int ty = tid >> 4, tx = tid & 15;

  float acc[8][8];
#pragma unroll
  for (int i = 0; i < 8; ++i)
#pragma unroll
    for (int j = 0; j < 8; ++j) acc[i][j] = 0.f;

  for (int k0 = 0; k0 < DD; k0 += GK) {
#pragma unroll
    for (int j = 0; j < 2; ++j) {
      int idx = j * 256 + tid;
      int r = idx >> 2;
      int kq = (idx & 3) * 4;
      float4 v = *(const float4*)&X[(size_t)(rt * GT + r) * DD + k0 + kq];
      As[kq + 0][r] = v.x; As[kq + 1][r] = v.y;
      As[kq + 2][r] = v.z; As[kq + 3][r] = v.w;
    }
#pragma unroll
    for (int j = 0; j < 2; ++j) {
      int idx = j * 256 + tid;
      int kk = idx >> 5;
      int cq = (idx & 31) * 4;
      *(float4*)&Bs[kk][cq] =
          *(const float4*)&Wb[(size_t)(k0 + kk) * DD + cc0 + cq];
    }
    __syncthreads();
#pragma unroll
    for (int k = 0; k < GK; ++k) {
      float a[8], bv[8];
      *(float4*)&a[0]  = *(const float4*)&As[k][ty * 8];
      *(float4*)&a[4]  = *(const float4*)&As[k][ty * 8 + 4];
      *(float4*)&bv[0] = *(const float4*)&Bs[k][tx * 8];
      *(float4*)&bv[4] = *(const float4*)&Bs[k][tx * 8 + 4];
#pragma unroll
      for (int i = 0; i < 8; ++i)
#pragma unroll
        for (int j = 0; j < 8; ++j) acc[i][j] = fmaf(a[i], bv[j], acc[i][j]);
    }
    __syncthreads();
  }

  float bias[8];
#pragma unroll
  for (int j = 0; j < 8; ++j) bias[j] = bb[tx * 8 + j];
#pragma unroll
  for (int i = 0; i < 8; ++i) {
    int t = rt * GT + ty * 8 + i;
    float4 o0 = make_float4(acc[i][0] + bias[0], acc[i][1] + bias[1],
                            acc[i][2] + bias[2], acc[i][3] + bias[3]);
    float4 o1 = make_float4(acc[i][4] + bias[4], acc[i][5] + bias[5],
                            acc[i][6] + bias[6], acc[i][7] + bias[7]);
    *(float4*)&ZX[(size_t)t * 4096 + c0 + tx * 8]     = o0;
    *(float4*)&ZX[(size_t)t * 4096 + c0 + tx * 8 + 4] = o1;
  }
}

// h-part recurrence with R-way replicated h-exchange.
// Replica 0 = Hout (also the next layer's input); replicas 1..R-1 in REP.
// Producer (wave 7) stores h per replica; reader block polls replica
// (bid & (R-1)) only -> readers-per-cache-line drops 256 -> 256/R.
__global__ __launch_bounds__(NTHR) void recur_kernel(
    const float* __restrict__ ZX,   // [TT, 4096], x-part incl. bias
    float* __restrict__ Hout,       // [TT, DD], NaN-prefilled
    float* __restrict__ REP,        // [R-1][TT, DD], NaN-prefilled
    int R,                          // replicas, power of 2, >=1
    const float* __restrict__ Wf1, const float* __restrict__ Wf2,
    const float* __restrict__ Wta, const float* __restrict__ Wtb,
    const float* __restrict__ dt_p, int layer,
    float* __restrict__ out_last)
{
  __shared__ float4 wlds[8 * 8 * 64];  // [wave][seg][lane] = 64 KB
  __shared__ float hs[DD];             // h_{t-1} broadcast (4 KB)
  __shared__ float zbuf[16];

  const int tid = threadIdx.x;
  const int w   = tid >> 6;            // wave 0..7
  const int ln  = tid & 63;
  const int bid = blockIdx.x;

  const int B    = w >> 1;
  const int p    = w & 1;
  const int col0 = bid * 4 + 2 * p;
  const float* Wsel = (B == 0) ? Wf1 : (B == 1) ? Wf2 : (B == 2) ? Wta : Wtb;
  const float* Wb = Wsel + (size_t)layer * 2 * DD * DD;
  const float dtv = dt_p[0];

  // This block reads replica (bid & (R-1)).
  const int rsel = bid & (R - 1);
  const float* hread = (rsel == 0) ? Hout : REP + (size_t)(rsel - 1) * TT * DD;
  // Producer lane ln (< R) writes replica ln.
  float* hwrite = (ln == 0) ? Hout : REP + (size_t)(ln - 1) * TT * DD;

  // Fill W_h into LDS: rows 1024 + s*128 + 2*ln (+1), cols col0, col0+1.
#pragma unroll
  for (int s = 0; s < 8; ++s) {
    const float* a_ = Wb + (size_t)(DD + s * 128 + 2 * ln) * DD + col0;
    float2 lo = *(const float2*)a_;
    float2 hi = *(const float2*)(a_ + DD);
    wlds[(w * 8 + s) * 64 + ln] = make_float4(lo.x, lo.y, hi.x, hi.y);
  }
  *(float2*)&hs[2 * tid] = make_float2(0.f, 0.f);   // h_{-1} = 0
  __syncthreads();

  for (int t = 0; t < TT; ++t) {
    float2 zx2 = make_float2(0.f, 0.f);
    if (ln == 0) zx2 = *(const float2*)&ZX[(size_t)t * 4096 + B * 1024 + col0];

    if (t > 0) {
      if (w == 7) {
        // Producer: gate math for h(t-1) (zbuf from prev iter), then one
        // 16B (2x8B) store per replica from lanes 0..R-1.
        float h = 0.f;
        if (ln < 4) {
          float z1 = zbuf[ln];
          float z2 = zbuf[4 + ln];
          float za = zbuf[8 + ln];
          float zb = zbuf[12 + ln];
          float f1 = fast_tanh(z1);
          float f2 = fast_tanh(z2);
          float g = 1.f / (1.f + __expf(za * dtv - zb));
          h = g * f1 + (1.f - g) * f2;
        }
        float4 hv = make_float4(__shfl(h, 0, 64), __shfl(h, 1, 64),
                                __shfl(h, 2, 64), __shfl(h, 3, 64));
        if (ln < R)
          agent_store16(&hwrite[(size_t)(t - 1) * DD + bid * 4], hv);
      } else if (w < 4) {
        // Pollers: wave w covers h words [w*256, w*256+256), 16B per lane,
        // from this block's replica only.
        const float* src = &hread[(size_t)(t - 1) * DD + w * 256 + ln * 4];
        float4 v; int guard = 0;
        while (true) {
          v = agent_load16(src);
          unsigned a0 = __float_as_uint(v.x) & 0x7fffffffu;
          unsigned a1 = __float_as_uint(v.y) & 0x7fffffffu;
          unsigned a2 = __float_as_uint(v.z) & 0x7fffffffu;
          unsigned a3 = __float_as_uint(v.w) & 0x7fffffffu;
          bool ok = (a0 <= 0x7f800000u) && (a1 <= 0x7f800000u) &&
                    (a2 <= 0x7f800000u) && (a3 <= 0x7f800000u);
          if (__all(ok)) break;
          if (++guard > (1 << 22)) break;
        }
        *(float4*)&hs[w * 256 + ln * 4] = v;
      }
    }
    __syncthreads();   // hs(t-1) ready

    // Dot: 2 cols per wave over the 1024 h rows (weights from LDS).
    float acc0 = 0.f, acc1 = 0.f;
#define DOTS(s) do {                                        \
      float4 m = wlds[(w * 8 + (s)) * 64 + ln];             \
      float2 v_ = *(const float2*)&hs[(s) * 128 + 2 * ln];  \
      acc0 = fmaf(v_.x, m.x, acc0);                         \
      acc0 = fmaf(v_.y, m.z, acc0);                         \
      acc1 = fmaf(v_.x, m.y, acc1);                         \
      acc1 = fmaf(v_.y, m.w, acc1);                         \
    } while (0)
    DOTS(0); DOTS(1); DOTS(2); DOTS(3);
    DOTS(4); DOTS(5); DOTS(6); DOTS(7);
#undef DOTS
#pragma unroll
    for (int off = 32; off > 0; off >>= 1) {
      acc0 += __shfl_xor(acc0, off, 64);
      acc1 += __shfl_xor(acc1, off, 64);
    }
    if (ln == 0) {
      zbuf[2 * w]     = acc0 + zx2.x;   // zbuf[B*4 + 2p + q]
      zbuf[2 * w + 1] = acc1 + zx2.y;
    }
    __syncthreads();   // zbuf(t) ready
  }

  // Epilogue: h(TT-1) -> Hout (next layer's xgemm input) and final output.
  if (w == 7 && ln < 4) {
    float z1 = zbuf[ln];
    float z2 = zbuf[4 + ln];
    float za = zbuf[8 + ln];
    float zb = zbuf[12 + ln];
    float f1 = fast_tanh(z1);
    float f2 = fast_tanh(z2);
    float g = 1.f / (1.f + __expf(za * dtv - zb));
    float h = g * f1 + (1.f - g) * f2;
    __hip_atomic_store(&Hout[(size_t)(TT - 1) * DD + bid * 4 + ln], h,
                       __ATOMIC_RELAXED, __HIP_MEMORY_SCOPE_AGENT);
    if (out_last) out_last[bid * 4 + ln] = h;
  }
}

extern "C" void kernel_launch(void* const* d_in, const int* in_sizes, int n_in,
                              void* d_out, int out_size, void* d_ws, size_t ws_size,
                              hipStream_t stream) {
  const float* sp  = (const float*)d_in[0];
  const float* rn  = (const float*)d_in[1];
  const float* dt  = (const float*)d_in[2];
  const float* rw  = (const float*)d_in[3];
  const float* rb  = (const float*)d_in[4];
  const float* Wf1 = (const float*)d_in[5];
  const float* bf1 = (const float*)d_in[6];
  const float* Wf2 = (const float*)d_in[7];
  const float* bf2 = (const float*)d_in[8];
  const float* Wta = (const float*)d_in[9];
  const float* bta = (const float*)d_in[10];
  const float* Wtb = (const float*)d_in[11];
  const float* btb = (const float*)d_in[12];

  float* ws = (float*)d_ws;
  float* A   = ws;                          // [TT, DD]
  float* Bb  = ws + (size_t)TT * DD;        // [TT, DD]
  float* ZX  = ws + (size_t)2 * TT * DD;    // [TT, 4096]
  float* REP = ws + (size_t)2 * TT * DD + (size_t)TT * 4096;  // [R-1][TT,DD]
  float* out = (float*)d_out;
  const size_t seqBytes = sizeof(float) * TT * DD;
  const size_t baseBytes = (size_t)(2 * TT * DD + TT * 4096) * sizeof(float);

  // Adaptive replica count (power of 2, max 8), limited by workspace size.
  // ws_size is constant across calls -> same work every call.
  int R = 1;
  for (int cand = 8; cand > 1; cand >>= 1)
    if (baseBytes + (size_t)(cand - 1) * seqBytes <= ws_size) { R = cand; break; }
  const size_t repBytes = (size_t)(R - 1) * seqBytes;

  dim3 ggrid(32, 16);

#define LAYER(lyr, Xbuf, Hbuf, lastout)                                        \
  do {                                                                         \
    (void)hipMemsetAsync(Hbuf, 0xFF, seqBytes, stream);                        \
    if (R > 1) { (void)hipMemsetAsync(REP, 0xFF, repBytes, stream); }          \
    xgemm_kernel<<<ggrid, 256, 0, stream>>>(Xbuf, Wf1, Wf2, Wta, Wtb,          \
        bf1, bf2, bta, btb, ZX, lyr);                                          \
    recur_kernel<<<NBLK, NTHR, 0, stream>>>(ZX, Hbuf, REP, R, Wf1, Wf2,        \
        Wta, Wtb, dt, lyr, lastout);                                           \
  } while (0)

  // L0: X0 -> A; h-seq -> Bb
  prep_kernel<<<(TT * DD) / 1024, 1024, 0, stream>>>(sp, rn, rw, rb, A);
  LAYER(0, A, Bb, nullptr);
  LAYER(1, Bb, A, nullptr);
  LAYER(2, A, Bb, nullptr);
  LAYER(3, Bb, A, out);
#undef LAYER
}